// Round 1
// baseline (663.690 us; speedup 1.0000x reference)
//
#include <hip/hip_runtime.h>

typedef unsigned short u16;
typedef __attribute__((ext_vector_type(8))) short bf16x8;
typedef __attribute__((ext_vector_type(4))) float f32x4;

#define NB 2
#define NS 2048
#define NDM 1024
#define NH 16

__device__ __forceinline__ u16 f2bf(float f) {
  union { float f; unsigned u; } v; v.f = f;
  return (u16)((v.u + 0x7fffu + ((v.u >> 16) & 1u)) >> 16);
}

__global__ __launch_bounds__(256) void cast_bf16(const float* __restrict__ in,
                                                 u16* __restrict__ out, int n4) {
  int i = blockIdx.x * 256 + threadIdx.x;
  if (i < n4) {
    const float4 v = reinterpret_cast<const float4*>(in)[i];
    ushort4 o; o.x = f2bf(v.x); o.y = f2bf(v.y); o.z = f2bf(v.z); o.w = f2bf(v.w);
    reinterpret_cast<ushort4*>(out)[i] = o;
  }
}

// in: f32 [1024][1024] row-major -> out: bf16 [1024][1024] = in^T
__global__ __launch_bounds__(256) void transpose_w(const float* __restrict__ in,
                                                   u16* __restrict__ out) {
  __shared__ float tile[32][33];
  int bx = blockIdx.x, by = blockIdx.y;
  int x = threadIdx.x & 31, y0 = threadIdx.x >> 5;
#pragma unroll
  for (int i = 0; i < 4; i++) {
    int y = y0 + i * 8;
    tile[y][x] = in[(by * 32 + y) * NDM + bx * 32 + x];
  }
  __syncthreads();
#pragma unroll
  for (int i = 0; i < 4; i++) {
    int y = y0 + i * 8;
    out[(bx * 32 + y) * NDM + by * 32 + x] = f2bf(tile[x][y]);
  }
}

// ---- 128x128-tile bf16 GEMM, B^T layout (W is [N][K] row-major), K = N = 1024 ----
// mode 0: out bf16 head-major  [((b*NH+h)*NS+s)*64 + d]
// mode 1: out bf16 transposed  [((b*NH+h)*64+d)*NS + s]   (for V)
// mode 2: out f32 row-major    [m*1024 + n]
struct GArgs { const u16* X; const u16* W; const float* bias; void* out; int mode; };

__global__ __launch_bounds__(256, 2) void gemm_bt(GArgs g0, GArgs g1, GArgs g2) {
  GArgs ga = (blockIdx.z == 0) ? g0 : (blockIdx.z == 1 ? g1 : g2);
  const int K = 1024, N = 1024;
  __shared__ u16 As[128 * 32];
  __shared__ u16 Bs[128 * 32];
  const int t = threadIdx.x, w = t >> 6, l = t & 63;
  const int m0 = blockIdx.x * 128, n0 = blockIdx.y * 128;
  const int wm = (w >> 1) * 64, wn = (w & 1) * 64;
  const f32x4 fz = {0.f, 0.f, 0.f, 0.f};
  f32x4 acc[4][4];
#pragma unroll
  for (int i = 0; i < 4; i++)
#pragma unroll
    for (int j = 0; j < 4; j++) acc[i][j] = fz;

  for (int k0 = 0; k0 < K; k0 += 32) {
#pragma unroll
    for (int i = 0; i < 2; i++) {
      int idx = i * 256 + w * 64 + l;        // linear 16B-chunk index, LDS dest = base + lane*16
      int r = idx >> 2, c = (idx & 3) * 8;
      __builtin_amdgcn_global_load_lds(
          reinterpret_cast<const unsigned*>(ga.X + (size_t)(m0 + r) * K + k0 + c),
          reinterpret_cast<unsigned*>(&As[(i * 256 + w * 64) * 8]), 16, 0, 0);
      __builtin_amdgcn_global_load_lds(
          reinterpret_cast<const unsigned*>(ga.W + (size_t)(n0 + r) * K + k0 + c),
          reinterpret_cast<unsigned*>(&Bs[(i * 256 + w * 64) * 8]), 16, 0, 0);
    }
    __syncthreads();
    bf16x8 af[4], bfr[4];
#pragma unroll
    for (int mt = 0; mt < 4; mt++)
      af[mt] = *reinterpret_cast<const bf16x8*>(&As[(wm + mt * 16 + (l & 15)) * 32 + (l >> 4) * 8]);
#pragma unroll
    for (int nt = 0; nt < 4; nt++)
      bfr[nt] = *reinterpret_cast<const bf16x8*>(&Bs[(wn + nt * 16 + (l & 15)) * 32 + (l >> 4) * 8]);
#pragma unroll
    for (int mt = 0; mt < 4; mt++)
#pragma unroll
      for (int nt = 0; nt < 4; nt++)
        acc[mt][nt] = __builtin_amdgcn_mfma_f32_16x16x32_bf16(af[mt], bfr[nt], acc[mt][nt], 0, 0, 0);
    __syncthreads();
  }

#pragma unroll
  for (int nt = 0; nt < 4; nt++) {
    int n = n0 + wn + nt * 16 + (l & 15);
    float bias = ga.bias[n];
#pragma unroll
    for (int mt = 0; mt < 4; mt++) {
      int mb = m0 + wm + mt * 16 + ((l >> 4) << 2);
#pragma unroll
      for (int r = 0; r < 4; r++) {
        int m = mb + r;
        float v = acc[mt][nt][r] + bias;
        if (ga.mode == 2) {
          reinterpret_cast<float*>(ga.out)[(size_t)m * N + n] = v;
        } else {
          int b = m >> 11, s = m & 2047, h = n >> 6, d = n & 63;
          if (ga.mode == 0)
            reinterpret_cast<u16*>(ga.out)[(((size_t)(b * NH + h) * NS + s) << 6) + d] = f2bf(v);
          else
            reinterpret_cast<u16*>(ga.out)[((size_t)(b * NH + h) * 64 + d) * NS + s] = f2bf(v);
        }
      }
    }
  }
}

// ---- attention: per (b,h,q-tile of 64 rows); 4 waves x 16 q-rows each ----
__global__ __launch_bounds__(256, 2) void attn_kernel(
    const u16* __restrict__ qh, const u16* __restrict__ kh, const u16* __restrict__ vT,
    const int* __restrict__ mask, float* __restrict__ attn, u16* __restrict__ ctx) {
  __shared__ u16 Ks[64 * 64];        // [kcol][d]
  __shared__ u16 Vs[64 * 64];        // [dv][kc]  (vT chunk)
  __shared__ u16 Ps[4][16 * 72];     // per-wave P tile, stride 72 (16B aligned, 2-way banks)
  const int t = threadIdx.x, w = t >> 6, l = t & 63;
  const int qt = blockIdx.x, h = blockIdx.y, b = blockIdx.z;
  const size_t head = (size_t)b * NH + h;
  const u16* qp = qh + head * NS * 64;
  const u16* kp = kh + head * NS * 64;
  const u16* vp = vT + head * 64 * NS;
  const int qr0 = qt * 64 + w * 16;
  const f32x4 fz = {0.f, 0.f, 0.f, 0.f};

  // mask storage-mode detection (harness bool mapping is ambiguous): int32 / byte / f32
  unsigned mw = reinterpret_cast<const unsigned*>(mask)[l];
  bool floatmode = (__ballot(mw == 0x3F800000u) != 0ull);
  bool bytemode = !floatmode && (__ballot((mw >> 8) != 0) != 0ull);
  const unsigned char* mask8 = reinterpret_cast<const unsigned char*>(mask);
  const float* maskf = reinterpret_cast<const float*>(mask);

  bf16x8 aq[2];
  {
    const u16* p = qp + (size_t)(qr0 + (l & 15)) * 64 + (l >> 4) * 8;
    aq[0] = *reinterpret_cast<const bf16x8*>(p);
    aq[1] = *reinterpret_cast<const bf16x8*>(p + 32);
  }

  float rs[4] = {0.f, 0.f, 0.f, 0.f};
  // ---- pass 1: row sums ----
  for (int c = 0; c < 32; c++) {
#pragma unroll
    for (int i = 0; i < 2; i++) {
      int idx = i * 256 + w * 64 + l;
      int kr = idx >> 3, off = (idx & 7) * 8;
      __builtin_amdgcn_global_load_lds(
          reinterpret_cast<const unsigned*>(kp + (size_t)(c * 64 + kr) * 64 + off),
          reinterpret_cast<unsigned*>(&Ks[(i * 256 + w * 64) * 8]), 16, 0, 0);
    }
    __syncthreads();
#pragma unroll
    for (int ct = 0; ct < 4; ct++) {
      f32x4 s = fz;
#pragma unroll
      for (int ks = 0; ks < 2; ks++) {
        bf16x8 bk = *reinterpret_cast<const bf16x8*>(
            &Ks[(ct * 16 + (l & 15)) * 64 + ks * 32 + (l >> 4) * 8]);
        s = __builtin_amdgcn_mfma_f32_16x16x32_bf16(aq[ks], bk, s, 0, 0, 0);
      }
      int kc = c * 64 + ct * 16 + (l & 15);
#pragma unroll
      for (int r = 0; r < 4; r++) {
        int qr = qr0 + ((l >> 4) << 2) + r;
        size_t mi = ((size_t)b * NS + qr) * NS + kc;
        bool msk = floatmode ? (maskf[mi] != 0.f) : (bytemode ? (mask8[mi] != 0) : (mask[mi] != 0));
        float p = msk ? 0.f : __expf(s[r] * 0.125f);
        rs[r] += p;
      }
    }
    __syncthreads();
  }
#pragma unroll
  for (int r = 0; r < 4; r++) {
    float v = rs[r];
    v += __shfl_xor(v, 1); v += __shfl_xor(v, 2);
    v += __shfl_xor(v, 4); v += __shfl_xor(v, 8);
    rs[r] = 1.f / fmaxf(v, 1e-30f);
  }

  // ---- pass 2: recompute, write attn, accumulate PV ----
  f32x4 cacc[4];
#pragma unroll
  for (int i = 0; i < 4; i++) cacc[i] = fz;
  for (int c = 0; c < 32; c++) {
#pragma unroll
    for (int i = 0; i < 2; i++) {
      int idx = i * 256 + w * 64 + l;
      int kr = idx >> 3, off = (idx & 7) * 8;
      __builtin_amdgcn_global_load_lds(
          reinterpret_cast<const unsigned*>(kp + (size_t)(c * 64 + kr) * 64 + off),
          reinterpret_cast<unsigned*>(&Ks[(i * 256 + w * 64) * 8]), 16, 0, 0);
      __builtin_amdgcn_global_load_lds(
          reinterpret_cast<const unsigned*>(vp + (size_t)kr * NS + c * 64 + off),
          reinterpret_cast<unsigned*>(&Vs[(i * 256 + w * 64) * 8]), 16, 0, 0);
    }
    __syncthreads();
#pragma unroll
    for (int ct = 0; ct < 4; ct++) {
      f32x4 s = fz;
#pragma unroll
      for (int ks = 0; ks < 2; ks++) {
        bf16x8 bk = *reinterpret_cast<const bf16x8*>(
            &Ks[(ct * 16 + (l & 15)) * 64 + ks * 32 + (l >> 4) * 8]);
        s = __builtin_amdgcn_mfma_f32_16x16x32_bf16(aq[ks], bk, s, 0, 0, 0);
      }
      int kc = c * 64 + ct * 16 + (l & 15);
#pragma unroll
      for (int r = 0; r < 4; r++) {
        int qr = qr0 + ((l >> 4) << 2) + r;
        size_t mi = ((size_t)b * NS + qr) * NS + kc;
        bool msk = floatmode ? (maskf[mi] != 0.f) : (bytemode ? (mask8[mi] != 0) : (mask[mi] != 0));
        float p = msk ? 0.f : __expf(s[r] * 0.125f);
        p *= rs[r];
        attn[(head * NS + qr) * NS + kc] = p;
        Ps[w][(((l >> 4) << 2) + r) * 72 + ct * 16 + (l & 15)] = f2bf(p);
      }
    }
    bf16x8 pa[2];
    pa[0] = *reinterpret_cast<const bf16x8*>(&Ps[w][(l & 15) * 72 + (l >> 4) * 8]);
    pa[1] = *reinterpret_cast<const bf16x8*>(&Ps[w][(l & 15) * 72 + 32 + (l >> 4) * 8]);
#pragma unroll
    for (int ct = 0; ct < 4; ct++) {
#pragma unroll
      for (int ks = 0; ks < 2; ks++) {
        bf16x8 bv = *reinterpret_cast<const bf16x8*>(
            &Vs[(ct * 16 + (l & 15)) * 64 + ks * 32 + (l >> 4) * 8]);
        cacc[ct] = __builtin_amdgcn_mfma_f32_16x16x32_bf16(pa[ks], bv, cacc[ct], 0, 0, 0);
      }
    }
    __syncthreads();
  }
#pragma unroll
  for (int ct = 0; ct < 4; ct++)
#pragma unroll
    for (int r = 0; r < 4; r++) {
      int qr = qr0 + ((l >> 4) << 2) + r;
      int dv = ct * 16 + (l & 15);
      ctx[((size_t)b * NS + qr) * 1024 + h * 64 + dv] = f2bf(cacc[ct][r]);
    }
}

extern "C" void kernel_launch(void* const* d_in, const int* in_sizes, int n_in,
                              void* d_out, int out_size, void* d_ws, size_t ws_size,
                              hipStream_t stream) {
  const float* Q = (const float*)d_in[0];
  const float* K = (const float*)d_in[1];
  const float* V = (const float*)d_in[2];
  const int* mask = (const int*)d_in[3];
  const float* wq = (const float*)d_in[4];
  const float* bq = (const float*)d_in[5];
  const float* wk = (const float*)d_in[6];
  const float* bk = (const float*)d_in[7];
  const float* wv = (const float*)d_in[8];
  const float* bv = (const float*)d_in[9];
  const float* wo = (const float*)d_in[10];
  const float* bo = (const float*)d_in[11];
  float* out = (float*)d_out;
  float* attn = out + (size_t)NB * NS * NDM;  // attn follows out, 134,217,728 f32

  // ws layout (64 MiB total)
  char* ws = (char*)d_ws;
  u16* Qb  = (u16*)(ws + 0);
  u16* Kb  = (u16*)(ws + 8388608);
  u16* Vb  = (u16*)(ws + 16777216);
  u16* wqT = (u16*)(ws + 25165824);
  u16* wkT = (u16*)(ws + 27262976);
  u16* wvT = (u16*)(ws + 29360128);
  u16* woT = (u16*)(ws + 31457280);
  u16* qhd = (u16*)(ws + 33554432);  // [b][h][s][64]
  u16* khd = (u16*)(ws + 41943040);  // [b][h][s][64]
  u16* vTd = (u16*)(ws + 50331648);  // [b][h][64][s]
  u16* ctx = (u16*)(ws + 58720256);  // [b*s][h*64+dv]

  cast_bf16<<<4096, 256, 0, stream>>>(Q, Qb, 1048576);
  cast_bf16<<<4096, 256, 0, stream>>>(K, Kb, 1048576);
  cast_bf16<<<4096, 256, 0, stream>>>(V, Vb, 1048576);
  transpose_w<<<dim3(32, 32), 256, 0, stream>>>(wq, wqT);
  transpose_w<<<dim3(32, 32), 256, 0, stream>>>(wk, wkT);
  transpose_w<<<dim3(32, 32), 256, 0, stream>>>(wv, wvT);
  transpose_w<<<dim3(32, 32), 256, 0, stream>>>(wo, woT);

  GArgs gq = {Qb, wqT, bq, (void*)qhd, 0};
  GArgs gk = {Kb, wkT, bk, (void*)khd, 0};
  GArgs gv = {Vb, wvT, bv, (void*)vTd, 1};
  gemm_bt<<<dim3(32, 8, 3), 256, 0, stream>>>(gq, gk, gv);

  attn_kernel<<<dim3(32, 16, 2), 256, 0, stream>>>(qhd, khd, vTd, mask, attn, ctx);

  GArgs go = {ctx, woT, bo, d_out, 2};
  gemm_bt<<<dim3(32, 8, 1), 256, 0, stream>>>(go, go, go);
}

// Round 2
// 625.933 us; speedup vs baseline: 1.0603x; 1.0603x over previous
//
#include <hip/hip_runtime.h>

typedef unsigned short u16;
typedef unsigned int u32;
typedef unsigned long long u64;
typedef __attribute__((ext_vector_type(8))) short bf16x8;
typedef __attribute__((ext_vector_type(4))) float f32x4;

#define NB 2
#define NS 2048
#define NDM 1024
#define NH 16

__device__ __forceinline__ u16 f2bf(float f) {
  union { float f; unsigned u; } v; v.f = f;
  return (u16)((v.u + 0x7fffu + ((v.u >> 16) & 1u)) >> 16);
}

__global__ __launch_bounds__(256) void cast_bf16(const float* __restrict__ in,
                                                 u16* __restrict__ out, int n4) {
  int i = blockIdx.x * 256 + threadIdx.x;
  if (i < n4) {
    const float4 v = reinterpret_cast<const float4*>(in)[i];
    ushort4 o; o.x = f2bf(v.x); o.y = f2bf(v.y); o.z = f2bf(v.z); o.w = f2bf(v.w);
    reinterpret_cast<ushort4*>(out)[i] = o;
  }
}

// in: f32 [1024][1024] row-major -> out: bf16 [1024][1024] = in^T
__global__ __launch_bounds__(256) void transpose_w(const float* __restrict__ in,
                                                   u16* __restrict__ out) {
  __shared__ float tile[32][33];
  int bx = blockIdx.x, by = blockIdx.y;
  int x = threadIdx.x & 31, y0 = threadIdx.x >> 5;
#pragma unroll
  for (int i = 0; i < 4; i++) {
    int y = y0 + i * 8;
    tile[y][x] = in[(by * 32 + y) * NDM + bx * 32 + x];
  }
  __syncthreads();
#pragma unroll
  for (int i = 0; i < 4; i++) {
    int y = y0 + i * 8;
    out[(bx * 32 + y) * NDM + by * 32 + x] = f2bf(tile[x][y]);
  }
}

// ---- mask [B,S,S] (int32 / packed-byte / f32 storage) -> bitmask, 1 bit/col, 64 u32 words per row ----
__global__ __launch_bounds__(256) void mask2bits(const u32* __restrict__ mask, u32* __restrict__ mb) {
  int idx = blockIdx.x * 256 + threadIdx.x;      // word index; total B*S*64 = 262144
  // storage-mode detection (same logic as validated R1 kernel)
  u32 mw0 = mask[threadIdx.x & 63];
  bool floatmode = (__ballot(mw0 == 0x3F800000u) != 0ull);
  bool bytemode = !floatmode && (__ballot((mw0 >> 8) != 0u) != 0ull);
  int row = idx >> 6;                            // b*2048 + s
  int wword = idx & 63;                          // 32 cols per word
  u32 bits = 0;
  if (!bytemode) {
    // word-per-bool (int32 or f32): nonzero word == true
    const uint4* p = reinterpret_cast<const uint4*>(mask + (size_t)row * 2048 + wword * 32);
#pragma unroll
    for (int i = 0; i < 8; i++) {
      uint4 v = p[i];
      bits |= (v.x ? 1u : 0u) << (i * 4 + 0);
      bits |= (v.y ? 1u : 0u) << (i * 4 + 1);
      bits |= (v.z ? 1u : 0u) << (i * 4 + 2);
      bits |= (v.w ? 1u : 0u) << (i * 4 + 3);
    }
  } else {
    const uint4* p = reinterpret_cast<const uint4*>(
        reinterpret_cast<const unsigned char*>(mask) + (size_t)row * 2048 + wword * 32);
#pragma unroll
    for (int i = 0; i < 2; i++) {
      uint4 v = p[i];
      u32 wsv[4] = {v.x, v.y, v.z, v.w};
#pragma unroll
      for (int j = 0; j < 4; j++)
#pragma unroll
        for (int kq = 0; kq < 4; kq++)
          bits |= ((((wsv[j] >> (kq * 8)) & 0xffu) != 0u) ? 1u : 0u) << (i * 16 + j * 4 + kq);
    }
  }
  mb[idx] = bits;
}

// ---- 128x128-tile bf16 GEMM, B^T layout (W is [N][K] row-major), K = N = 1024 ----
struct GArgs { const u16* X; const u16* W; const float* bias; void* out; int mode; };

__global__ __launch_bounds__(256, 2) void gemm_bt(GArgs g0, GArgs g1, GArgs g2) {
  GArgs ga = (blockIdx.z == 0) ? g0 : (blockIdx.z == 1 ? g1 : g2);
  const int K = 1024, N = 1024;
  __shared__ u16 As[128 * 32];
  __shared__ u16 Bs[128 * 32];
  const int t = threadIdx.x, w = t >> 6, l = t & 63;
  const int m0 = blockIdx.x * 128, n0 = blockIdx.y * 128;
  const int wm = (w >> 1) * 64, wn = (w & 1) * 64;
  const f32x4 fz = {0.f, 0.f, 0.f, 0.f};
  f32x4 acc[4][4];
#pragma unroll
  for (int i = 0; i < 4; i++)
#pragma unroll
    for (int j = 0; j < 4; j++) acc[i][j] = fz;

  for (int k0 = 0; k0 < K; k0 += 32) {
#pragma unroll
    for (int i = 0; i < 2; i++) {
      int idx = i * 256 + w * 64 + l;
      int r = idx >> 2, c = (idx & 3) * 8;
      __builtin_amdgcn_global_load_lds(
          reinterpret_cast<const unsigned*>(ga.X + (size_t)(m0 + r) * K + k0 + c),
          reinterpret_cast<unsigned*>(&As[(i * 256 + w * 64) * 8]), 16, 0, 0);
      __builtin_amdgcn_global_load_lds(
          reinterpret_cast<const unsigned*>(ga.W + (size_t)(n0 + r) * K + k0 + c),
          reinterpret_cast<unsigned*>(&Bs[(i * 256 + w * 64) * 8]), 16, 0, 0);
    }
    __syncthreads();
    bf16x8 af[4], bfr[4];
#pragma unroll
    for (int mt = 0; mt < 4; mt++)
      af[mt] = *reinterpret_cast<const bf16x8*>(&As[(wm + mt * 16 + (l & 15)) * 32 + (l >> 4) * 8]);
#pragma unroll
    for (int nt = 0; nt < 4; nt++)
      bfr[nt] = *reinterpret_cast<const bf16x8*>(&Bs[(wn + nt * 16 + (l & 15)) * 32 + (l >> 4) * 8]);
#pragma unroll
    for (int mt = 0; mt < 4; mt++)
#pragma unroll
      for (int nt = 0; nt < 4; nt++)
        acc[mt][nt] = __builtin_amdgcn_mfma_f32_16x16x32_bf16(af[mt], bfr[nt], acc[mt][nt], 0, 0, 0);
    __syncthreads();
  }

#pragma unroll
  for (int nt = 0; nt < 4; nt++) {
    int n = n0 + wn + nt * 16 + (l & 15);
    float bias = ga.bias[n];
#pragma unroll
    for (int mt = 0; mt < 4; mt++) {
      int mb = m0 + wm + mt * 16 + ((l >> 4) << 2);
#pragma unroll
      for (int r = 0; r < 4; r++) {
        int m = mb + r;
        float v = acc[mt][nt][r] + bias;
        if (ga.mode == 2) {
          reinterpret_cast<float*>(ga.out)[(size_t)m * N + n] = v;
        } else {
          int b = m >> 11, s = m & 2047, h = n >> 6, d = n & 63;
          if (ga.mode == 0)
            reinterpret_cast<u16*>(ga.out)[(((size_t)(b * NH + h) * NS + s) << 6) + d] = f2bf(v);
          else
            reinterpret_cast<u16*>(ga.out)[((size_t)(b * NH + h) * 64 + d) * NS + s] = f2bf(v);
        }
      }
    }
  }
}

// ---- attention: barrier-free. Each wave owns 16 q-rows; K/V fragments straight from L2. ----
__global__ __launch_bounds__(256) void attn_kernel(
    const u16* __restrict__ qh, const u16* __restrict__ kh, const u16* __restrict__ vT,
    const u64* __restrict__ mb64, float* __restrict__ attn, u16* __restrict__ ctx) {
  __shared__ u16 Ps[4][16 * 72];     // per-wave bf16 P tile (MFMA A-frag relayout)
  __shared__ float Pf[4][16 * 68];   // per-wave f32 P tile (vectorized attn stores)
  const int t = threadIdx.x, w = t >> 6, l = t & 63;
  // XCD-chunked bijective swizzle: all 32 q-tiles of one (b,h) land on one XCD -> K/V L2-resident
  int id = blockIdx.x;                       // 1024 blocks
  int wgid = (id & 7) * 128 + (id >> 3);
  int qt = wgid & 31, pr = wgid >> 5;
  int h = pr & 15, b = pr >> 4;
  const size_t head = (size_t)b * NH + h;
  const u16* qp = qh + head * NS * 64;
  const u16* kp = kh + head * NS * 64;
  const u16* vp = vT + head * 64 * NS;
  const int qr0 = qt * 64 + w * 16;
  const int lo = l & 15, hi = l >> 4;
  const int rbase = hi << 2;
  const f32x4 fz = {0.f, 0.f, 0.f, 0.f};

  bf16x8 aq[2];
  {
    const u16* p = qp + (size_t)(qr0 + lo) * 64 + hi * 8;
    aq[0] = *reinterpret_cast<const bf16x8*>(p);
    aq[1] = *reinterpret_cast<const bf16x8*>(p + 32);
  }
  const u64* mrow = mb64 + ((size_t)b * NS + qr0 + rbase) * 32;  // 32 u64 per row

  // ---- pass 1: row sums (no stores, no barriers) ----
  float rs[4] = {0.f, 0.f, 0.f, 0.f};
  for (int c = 0; c < 32; ++c) {
    u64 mwv[4] = {mrow[c], mrow[32 + c], mrow[64 + c], mrow[96 + c]};
#pragma unroll
    for (int ct = 0; ct < 4; ++ct) {
      f32x4 s = fz;
#pragma unroll
      for (int ks = 0; ks < 2; ++ks) {
        bf16x8 bk = *reinterpret_cast<const bf16x8*>(
            kp + (size_t)(c * 64 + ct * 16 + lo) * 64 + ks * 32 + hi * 8);
        s = __builtin_amdgcn_mfma_f32_16x16x32_bf16(aq[ks], bk, s, 0, 0, 0);
      }
      int bit = ct * 16 + lo;
#pragma unroll
      for (int r = 0; r < 4; ++r) {
        float p = ((mwv[r] >> bit) & 1ull) ? 0.f : __expf(s[r] * 0.125f);
        rs[r] += p;
      }
    }
  }
#pragma unroll
  for (int r = 0; r < 4; ++r) {
    float v = rs[r];
    v += __shfl_xor(v, 1); v += __shfl_xor(v, 2);
    v += __shfl_xor(v, 4); v += __shfl_xor(v, 8);
    rs[r] = 1.f / fmaxf(v, 1e-30f);
  }

  // ---- pass 2: recompute, write attn (vectorized via LDS), accumulate PV ----
  f32x4 cacc[4];
#pragma unroll
  for (int i = 0; i < 4; i++) cacc[i] = fz;
  u16* psw = &Ps[w][0];
  float* pfw = &Pf[w][0];
  for (int c = 0; c < 32; ++c) {
    u64 mwv[4] = {mrow[c], mrow[32 + c], mrow[64 + c], mrow[96 + c]};
#pragma unroll
    for (int ct = 0; ct < 4; ++ct) {
      f32x4 s = fz;
#pragma unroll
      for (int ks = 0; ks < 2; ++ks) {
        bf16x8 bk = *reinterpret_cast<const bf16x8*>(
            kp + (size_t)(c * 64 + ct * 16 + lo) * 64 + ks * 32 + hi * 8);
        s = __builtin_amdgcn_mfma_f32_16x16x32_bf16(aq[ks], bk, s, 0, 0, 0);
      }
      int bit = ct * 16 + lo;
#pragma unroll
      for (int r = 0; r < 4; ++r) {
        float p = ((mwv[r] >> bit) & 1ull) ? 0.f : __expf(s[r] * 0.125f);
        p *= rs[r];
        psw[(rbase + r) * 72 + ct * 16 + lo] = f2bf(p);
        pfw[(rbase + r) * 68 + ct * 16 + lo] = p;
      }
    }
    // coalesced attn stores: 4 rows x 256B contiguous per instruction
#pragma unroll
    for (int i2 = 0; i2 < 4; ++i2) {
      int row = i2 * 4 + hi;
      f32x4 pv4 = *reinterpret_cast<const f32x4*>(&pfw[row * 68 + lo * 4]);
      *reinterpret_cast<f32x4*>(attn + ((head * NS) + qr0 + row) * NS + c * 64 + lo * 4) = pv4;
    }
    // PV accumulate
    bf16x8 pa0 = *reinterpret_cast<const bf16x8*>(&psw[lo * 72 + hi * 8]);
    bf16x8 pa1 = *reinterpret_cast<const bf16x8*>(&psw[lo * 72 + 32 + hi * 8]);
#pragma unroll
    for (int ct = 0; ct < 4; ++ct) {
      const u16* vrow = vp + (size_t)(ct * 16 + lo) * NS + c * 64 + hi * 8;
      bf16x8 bv0 = *reinterpret_cast<const bf16x8*>(vrow);
      bf16x8 bv1 = *reinterpret_cast<const bf16x8*>(vrow + 32);
      cacc[ct] = __builtin_amdgcn_mfma_f32_16x16x32_bf16(pa0, bv0, cacc[ct], 0, 0, 0);
      cacc[ct] = __builtin_amdgcn_mfma_f32_16x16x32_bf16(pa1, bv1, cacc[ct], 0, 0, 0);
    }
  }
#pragma unroll
  for (int ct = 0; ct < 4; ++ct)
#pragma unroll
    for (int r = 0; r < 4; ++r) {
      int qr = qr0 + rbase + r;
      int dv = ct * 16 + lo;
      ctx[((size_t)b * NS + qr) * 1024 + h * 64 + dv] = f2bf(cacc[ct][r]);
    }
}

extern "C" void kernel_launch(void* const* d_in, const int* in_sizes, int n_in,
                              void* d_out, int out_size, void* d_ws, size_t ws_size,
                              hipStream_t stream) {
  const float* Q = (const float*)d_in[0];
  const float* K = (const float*)d_in[1];
  const float* V = (const float*)d_in[2];
  const u32* mask = (const u32*)d_in[3];
  const float* wq = (const float*)d_in[4];
  const float* bq = (const float*)d_in[5];
  const float* wk = (const float*)d_in[6];
  const float* bk = (const float*)d_in[7];
  const float* wv = (const float*)d_in[8];
  const float* bv = (const float*)d_in[9];
  const float* wo = (const float*)d_in[10];
  const float* bo = (const float*)d_in[11];
  float* out = (float*)d_out;
  float* attn = out + (size_t)NB * NS * NDM;

  char* ws = (char*)d_ws;
  u16* Qb  = (u16*)(ws + 0);          // dead after proj GEMM; reused for mbits
  u16* Kb  = (u16*)(ws + 8388608);
  u16* Vb  = (u16*)(ws + 16777216);
  u16* wqT = (u16*)(ws + 25165824);
  u16* wkT = (u16*)(ws + 27262976);
  u16* wvT = (u16*)(ws + 29360128);
  u16* woT = (u16*)(ws + 31457280);
  u16* qhd = (u16*)(ws + 33554432);   // [b][h][s][64]
  u16* khd = (u16*)(ws + 41943040);   // [b][h][s][64]
  u16* vTd = (u16*)(ws + 50331648);   // [b][h][64][s]
  u16* ctx = (u16*)(ws + 58720256);   // [b*s][h*64+dv]
  u32* mbits = (u32*)(ws + 0);        // 1 MB, written after Qb is consumed

  cast_bf16<<<4096, 256, 0, stream>>>(Q, Qb, 1048576);
  cast_bf16<<<4096, 256, 0, stream>>>(K, Kb, 1048576);
  cast_bf16<<<4096, 256, 0, stream>>>(V, Vb, 1048576);
  transpose_w<<<dim3(32, 32), 256, 0, stream>>>(wq, wqT);
  transpose_w<<<dim3(32, 32), 256, 0, stream>>>(wk, wkT);
  transpose_w<<<dim3(32, 32), 256, 0, stream>>>(wv, wvT);
  transpose_w<<<dim3(32, 32), 256, 0, stream>>>(wo, woT);

  GArgs gq = {Qb, wqT, bq, (void*)qhd, 0};
  GArgs gk = {Kb, wkT, bk, (void*)khd, 0};
  GArgs gv = {Vb, wvT, bv, (void*)vTd, 1};
  gemm_bt<<<dim3(32, 8, 3), 256, 0, stream>>>(gq, gk, gv);

  mask2bits<<<1024, 256, 0, stream>>>(mask, mbits);   // overwrites Qb region (now dead)

  attn_kernel<<<1024, 256, 0, stream>>>(qhd, khd, vTd, (const u64*)mbits, attn, ctx);

  GArgs go = {ctx, woT, bo, d_out, 2};
  gemm_bt<<<dim3(32, 8, 1), 256, 0, stream>>>(go, go, go);
}

// Round 3
// 537.377 us; speedup vs baseline: 1.2351x; 1.1648x over previous
//
#include <hip/hip_runtime.h>

typedef unsigned short u16;
typedef unsigned int u32;
typedef unsigned long long u64;
typedef __attribute__((ext_vector_type(8))) short bf16x8;
typedef __attribute__((ext_vector_type(4))) float f32x4;

#define NB 2
#define NS 2048
#define NDM 1024
#define NH 16

__device__ __forceinline__ u16 f2bf(float f) {
  union { float f; unsigned u; } v; v.f = f;
  return (u16)((v.u + 0x7fffu + ((v.u >> 16) & 1u)) >> 16);
}

__global__ __launch_bounds__(256) void cast_bf16(const float* __restrict__ in,
                                                 u16* __restrict__ out, int n4) {
  int i = blockIdx.x * 256 + threadIdx.x;
  if (i < n4) {
    const float4 v = reinterpret_cast<const float4*>(in)[i];
    ushort4 o; o.x = f2bf(v.x); o.y = f2bf(v.y); o.z = f2bf(v.z); o.w = f2bf(v.w);
    reinterpret_cast<ushort4*>(out)[i] = o;
  }
}

// in: f32 [1024][1024] row-major -> out: bf16 [1024][1024] = in^T
__global__ __launch_bounds__(256) void transpose_w(const float* __restrict__ in,
                                                   u16* __restrict__ out) {
  __shared__ float tile[32][33];
  int bx = blockIdx.x, by = blockIdx.y;
  int x = threadIdx.x & 31, y0 = threadIdx.x >> 5;
#pragma unroll
  for (int i = 0; i < 4; i++) {
    int y = y0 + i * 8;
    tile[y][x] = in[(by * 32 + y) * NDM + bx * 32 + x];
  }
  __syncthreads();
#pragma unroll
  for (int i = 0; i < 4; i++) {
    int y = y0 + i * 8;
    out[(bx * 32 + y) * NDM + by * 32 + x] = f2bf(tile[x][y]);
  }
}

// ---- mask [B,S,S] -> bitmask, 1 bit/col ----
__global__ __launch_bounds__(256) void mask2bits(const u32* __restrict__ mask, u32* __restrict__ mb) {
  int idx = blockIdx.x * 256 + threadIdx.x;
  u32 mw0 = mask[threadIdx.x & 63];
  bool floatmode = (__ballot(mw0 == 0x3F800000u) != 0ull);
  bool bytemode = !floatmode && (__ballot((mw0 >> 8) != 0u) != 0ull);
  int row = idx >> 6;
  int wword = idx & 63;
  u32 bits = 0;
  if (!bytemode) {
    const uint4* p = reinterpret_cast<const uint4*>(mask + (size_t)row * 2048 + wword * 32);
#pragma unroll
    for (int i = 0; i < 8; i++) {
      uint4 v = p[i];
      bits |= (v.x ? 1u : 0u) << (i * 4 + 0);
      bits |= (v.y ? 1u : 0u) << (i * 4 + 1);
      bits |= (v.z ? 1u : 0u) << (i * 4 + 2);
      bits |= (v.w ? 1u : 0u) << (i * 4 + 3);
    }
  } else {
    const uint4* p = reinterpret_cast<const uint4*>(
        reinterpret_cast<const unsigned char*>(mask) + (size_t)row * 2048 + wword * 32);
#pragma unroll
    for (int i = 0; i < 2; i++) {
      uint4 v = p[i];
      u32 wsv[4] = {v.x, v.y, v.z, v.w};
#pragma unroll
      for (int j = 0; j < 4; j++)
#pragma unroll
        for (int kq = 0; kq < 4; kq++)
          bits |= ((((wsv[j] >> (kq * 8)) & 0xffu) != 0u) ? 1u : 0u) << (i * 16 + j * 4 + kq);
    }
  }
  mb[idx] = bits;
}

// ---- 128x128-tile bf16 GEMM, B^T layout ----
struct GArgs { const u16* X; const u16* W; const float* bias; void* out; int mode; float scale; };

__global__ __launch_bounds__(256, 2) void gemm_bt(GArgs g0, GArgs g1, GArgs g2) {
  GArgs ga = (blockIdx.z == 0) ? g0 : (blockIdx.z == 1 ? g1 : g2);
  const int K = 1024, N = 1024;
  __shared__ u16 As[128 * 32];
  __shared__ u16 Bs[128 * 32];
  const int t = threadIdx.x, w = t >> 6, l = t & 63;
  const int m0 = blockIdx.x * 128, n0 = blockIdx.y * 128;
  const int wm = (w >> 1) * 64, wn = (w & 1) * 64;
  const f32x4 fz = {0.f, 0.f, 0.f, 0.f};
  f32x4 acc[4][4];
#pragma unroll
  for (int i = 0; i < 4; i++)
#pragma unroll
    for (int j = 0; j < 4; j++) acc[i][j] = fz;

  for (int k0 = 0; k0 < K; k0 += 32) {
#pragma unroll
    for (int i = 0; i < 2; i++) {
      int idx = i * 256 + w * 64 + l;
      int r = idx >> 2, c = (idx & 3) * 8;
      __builtin_amdgcn_global_load_lds(
          reinterpret_cast<const unsigned*>(ga.X + (size_t)(m0 + r) * K + k0 + c),
          reinterpret_cast<unsigned*>(&As[(i * 256 + w * 64) * 8]), 16, 0, 0);
      __builtin_amdgcn_global_load_lds(
          reinterpret_cast<const unsigned*>(ga.W + (size_t)(n0 + r) * K + k0 + c),
          reinterpret_cast<unsigned*>(&Bs[(i * 256 + w * 64) * 8]), 16, 0, 0);
    }
    __syncthreads();
    bf16x8 af[4], bfr[4];
#pragma unroll
    for (int mt = 0; mt < 4; mt++)
      af[mt] = *reinterpret_cast<const bf16x8*>(&As[(wm + mt * 16 + (l & 15)) * 32 + (l >> 4) * 8]);
#pragma unroll
    for (int nt = 0; nt < 4; nt++)
      bfr[nt] = *reinterpret_cast<const bf16x8*>(&Bs[(wn + nt * 16 + (l & 15)) * 32 + (l >> 4) * 8]);
#pragma unroll
    for (int mt = 0; mt < 4; mt++)
#pragma unroll
      for (int nt = 0; nt < 4; nt++)
        acc[mt][nt] = __builtin_amdgcn_mfma_f32_16x16x32_bf16(af[mt], bfr[nt], acc[mt][nt], 0, 0, 0);
    __syncthreads();
  }

#pragma unroll
  for (int nt = 0; nt < 4; nt++) {
    int n = n0 + wn + nt * 16 + (l & 15);
    float bias = ga.bias[n];
#pragma unroll
    for (int mt = 0; mt < 4; mt++) {
      int mb = m0 + wm + mt * 16 + ((l >> 4) << 2);
#pragma unroll
      for (int r = 0; r < 4; r++) {
        int m = mb + r;
        float v = (acc[mt][nt][r] + bias) * ga.scale;
        if (ga.mode == 2) {
          reinterpret_cast<float*>(ga.out)[(size_t)m * N + n] = v;
        } else {
          int b = m >> 11, s = m & 2047, h = n >> 6, d = n & 63;
          if (ga.mode == 0)
            reinterpret_cast<u16*>(ga.out)[(((size_t)(b * NH + h) * NS + s) << 6) + d] = f2bf(v);
          else
            reinterpret_cast<u16*>(ga.out)[((size_t)(b * NH + h) * 64 + d) * NS + s] = f2bf(v);
        }
      }
    }
  }
}

// ---- attention: barrier-free, explicit K-frag double-buffer for MLP ----
__global__ __launch_bounds__(256, 3) void attn_kernel(
    const u16* __restrict__ qh, const u16* __restrict__ kh, const u16* __restrict__ vT,
    const u64* __restrict__ mb64, float* __restrict__ attn, u16* __restrict__ ctx) {
  __shared__ u16 Ps[4][16 * 72];
  const int t = threadIdx.x, w = t >> 6, l = t & 63;
  int id = blockIdx.x;
  int wgid = (id & 7) * 128 + (id >> 3);   // XCD-chunked bijective swizzle (1024 % 8 == 0)
  int qt = wgid & 31, pr = wgid >> 5;
  int h = pr & 15, b = pr >> 4;
  const size_t head = (size_t)b * NH + h;
  const u16* qp = qh + head * NS * 64;
  const u16* kp = kh + head * NS * 64;
  const u16* vp = vT + head * 64 * NS;
  const int qr0 = qt * 64 + w * 16;
  const int lo = l & 15, hi = l >> 4;
  const int rbase = hi << 2;
  const f32x4 fz = {0.f, 0.f, 0.f, 0.f};

  bf16x8 aq0, aq1;
  {
    const u16* p = qp + (size_t)(qr0 + lo) * 64 + hi * 8;
    aq0 = *reinterpret_cast<const bf16x8*>(p);
    aq1 = *reinterpret_cast<const bf16x8*>(p + 32);
  }
  const u64* mrow = mb64 + ((size_t)b * NS + qr0 + rbase) * 32;

  auto loadK = [&](bf16x8* dst, int c) {
    const u16* kb = kp + (size_t)(c * 64) * 64;
#pragma unroll
    for (int ct = 0; ct < 4; ++ct) {
      const u16* p = kb + (size_t)(ct * 16 + lo) * 64 + hi * 8;
      dst[2 * ct] = *reinterpret_cast<const bf16x8*>(p);
      dst[2 * ct + 1] = *reinterpret_cast<const bf16x8*>(p + 32);
    }
  };
  auto qk = [&](const bf16x8* bk, f32x4* s) {
#pragma unroll
    for (int ct = 0; ct < 4; ++ct) {
      f32x4 acc = fz;
      acc = __builtin_amdgcn_mfma_f32_16x16x32_bf16(aq0, bk[2 * ct], acc, 0, 0, 0);
      acc = __builtin_amdgcn_mfma_f32_16x16x32_bf16(aq1, bk[2 * ct + 1], acc, 0, 0, 0);
      s[ct] = acc;
    }
  };

  // ---- pass 1: row sums only (q pre-scaled by 1/8 in projection) ----
  float rs[4] = {0.f, 0.f, 0.f, 0.f};
  {
    bf16x8 bkA[8], bkB[8];
    loadK(bkA, 0);
    for (int c = 0; c < 32; c += 2) {
      loadK(bkB, c + 1);
      {
        u64 mwv[4] = {mrow[c], mrow[32 + c], mrow[64 + c], mrow[96 + c]};
        f32x4 s[4]; qk(bkA, s);
#pragma unroll
        for (int ct = 0; ct < 4; ++ct) {
          int bit = ct * 16 + lo;
#pragma unroll
          for (int r = 0; r < 4; ++r)
            rs[r] += ((mwv[r] >> bit) & 1ull) ? 0.f : __expf(s[ct][r]);
        }
      }
      if (c + 2 < 32) loadK(bkA, c + 2);
      {
        int c1 = c + 1;
        u64 mwv[4] = {mrow[c1], mrow[32 + c1], mrow[64 + c1], mrow[96 + c1]};
        f32x4 s[4]; qk(bkB, s);
#pragma unroll
        for (int ct = 0; ct < 4; ++ct) {
          int bit = ct * 16 + lo;
#pragma unroll
          for (int r = 0; r < 4; ++r)
            rs[r] += ((mwv[r] >> bit) & 1ull) ? 0.f : __expf(s[ct][r]);
        }
      }
    }
  }
#pragma unroll
  for (int r = 0; r < 4; ++r) {
    float v = rs[r];
    v += __shfl_xor(v, 1); v += __shfl_xor(v, 2);
    v += __shfl_xor(v, 4); v += __shfl_xor(v, 8);
    rs[r] = 1.f / fmaxf(v, 1e-30f);
  }

  // ---- pass 2: recompute, direct attn stores, PV ----
  f32x4 cacc[4];
#pragma unroll
  for (int i = 0; i < 4; i++) cacc[i] = fz;
  u16* psw = &Ps[w][0];
  float* arow = attn + (head * NS + qr0 + rbase) * NS + lo;

  {
    bf16x8 bkA[8], bkB[8];
    loadK(bkA, 0);
    for (int c = 0; c < 32; c += 2) {
      loadK(bkB, c + 1);
#pragma unroll
      for (int half = 0; half < 2; ++half) {
        int cc = c + half;
        const bf16x8* bk = half ? bkB : bkA;
        u64 mwv[4] = {mrow[cc], mrow[32 + cc], mrow[64 + cc], mrow[96 + cc]};
        f32x4 s[4]; qk(bk, s);
        if (half == 0 && c + 2 < 32) loadK(bkA, c + 2);
        // V fragments for this chunk (issued before the exp chain to hide latency)
        bf16x8 bv[8];
        {
          const u16* vb = vp + cc * 64;
#pragma unroll
          for (int ct = 0; ct < 4; ++ct) {
            const u16* p = vb + (size_t)(ct * 16 + lo) * NS + hi * 8;
            bv[2 * ct] = *reinterpret_cast<const bf16x8*>(p);
            bv[2 * ct + 1] = *reinterpret_cast<const bf16x8*>(p + 32);
          }
        }
#pragma unroll
        for (int ct = 0; ct < 4; ++ct) {
          int bit = ct * 16 + lo;
#pragma unroll
          for (int r = 0; r < 4; ++r) {
            float p = ((mwv[r] >> bit) & 1ull) ? 0.f : __expf(s[ct][r]) * rs[r];
            arow[(size_t)r * NS + cc * 64 + ct * 16] = p;        // direct dword store
            psw[(rbase + r) * 72 + ct * 16 + lo] = f2bf(p);
          }
        }
        bf16x8 pa0 = *reinterpret_cast<const bf16x8*>(&psw[lo * 72 + hi * 8]);
        bf16x8 pa1 = *reinterpret_cast<const bf16x8*>(&psw[lo * 72 + 32 + hi * 8]);
#pragma unroll
        for (int ct = 0; ct < 4; ++ct) {
          cacc[ct] = __builtin_amdgcn_mfma_f32_16x16x32_bf16(pa0, bv[2 * ct], cacc[ct], 0, 0, 0);
          cacc[ct] = __builtin_amdgcn_mfma_f32_16x16x32_bf16(pa1, bv[2 * ct + 1], cacc[ct], 0, 0, 0);
        }
      }
    }
  }
#pragma unroll
  for (int ct = 0; ct < 4; ++ct)
#pragma unroll
    for (int r = 0; r < 4; ++r) {
      int qr = qr0 + rbase + r;
      int dv = ct * 16 + lo;
      ctx[((size_t)b * NS + qr) * 1024 + h * 64 + dv] = f2bf(cacc[ct][r]);
    }
}

extern "C" void kernel_launch(void* const* d_in, const int* in_sizes, int n_in,
                              void* d_out, int out_size, void* d_ws, size_t ws_size,
                              hipStream_t stream) {
  const float* Q = (const float*)d_in[0];
  const float* K = (const float*)d_in[1];
  const float* V = (const float*)d_in[2];
  const u32* mask = (const u32*)d_in[3];
  const float* wq = (const float*)d_in[4];
  const float* bq = (const float*)d_in[5];
  const float* wk = (const float*)d_in[6];
  const float* bk = (const float*)d_in[7];
  const float* wv = (const float*)d_in[8];
  const float* bv = (const float*)d_in[9];
  const float* wo = (const float*)d_in[10];
  const float* bo = (const float*)d_in[11];
  float* out = (float*)d_out;
  float* attn = out + (size_t)NB * NS * NDM;

  char* ws = (char*)d_ws;
  u16* Qb  = (u16*)(ws + 0);
  u16* Kb  = (u16*)(ws + 8388608);
  u16* Vb  = (u16*)(ws + 16777216);
  u16* wqT = (u16*)(ws + 25165824);
  u16* wkT = (u16*)(ws + 27262976);
  u16* wvT = (u16*)(ws + 29360128);
  u16* wvU = (u16*)(ws + 31457280);
  u16* woT = (u16*)(ws + 31457280);
  u16* qhd = (u16*)(ws + 33554432);
  u16* khd = (u16*)(ws + 41943040);
  u16* vTd = (u16*)(ws + 50331648);
  u16* ctx = (u16*)(ws + 58720256);
  u32* mbits = (u32*)(ws + 0);
  (void)wvU;

  cast_bf16<<<4096, 256, 0, stream>>>(Q, Qb, 1048576);
  cast_bf16<<<4096, 256, 0, stream>>>(K, Kb, 1048576);
  cast_bf16<<<4096, 256, 0, stream>>>(V, Vb, 1048576);
  transpose_w<<<dim3(32, 32), 256, 0, stream>>>(wq, wqT);
  transpose_w<<<dim3(32, 32), 256, 0, stream>>>(wk, wkT);
  transpose_w<<<dim3(32, 32), 256, 0, stream>>>(wv, wvT);
  transpose_w<<<dim3(32, 32), 256, 0, stream>>>(wo, woT);

  GArgs gq = {Qb, wqT, bq, (void*)qhd, 0, 0.125f};   // fold 1/sqrt(dk) into q
  GArgs gk = {Kb, wkT, bk, (void*)khd, 0, 1.0f};
  GArgs gv = {Vb, wvT, bv, (void*)vTd, 1, 1.0f};
  gemm_bt<<<dim3(32, 8, 3), 256, 0, stream>>>(gq, gk, gv);

  mask2bits<<<1024, 256, 0, stream>>>(mask, mbits);

  attn_kernel<<<1024, 256, 0, stream>>>(qhd, khd, vTd, (const u64*)mbits, attn, ctx);

  GArgs go = {ctx, woT, bo, d_out, 2, 1.0f};
  gemm_bt<<<dim3(32, 8, 1), 256, 0, stream>>>(go, go, go);
}